// Round 9
// baseline (213.369 us; speedup 1.0000x reference)
//
#include <hip/hip_runtime.h>
#include <hip/hip_bf16.h>

// MHA forward.  B=1, S=2048, H=1024, NH=16, DK=64.
// Inputs fp32, output fp32.  Internal bf16 MFMA pipeline, fp32 accum.
// Quirk: masked scores -> 0 (not -inf) BEFORE softmax; |scores| <= ~2 so
// softmax needs no max subtraction (m=0) and KV-split partials add.
// R9: attn 64-q/4-wave blocks (41KB LDS -> 3 blocks/CU); exp2-folded Q
// scale (bare v_exp_f32); QKV GEMM takes fp32 A directly (cvt = W only).

#define S_LEN 2048
#define HID   1024
#define NHEAD 16
#define DK    64

typedef unsigned short u16;
typedef __attribute__((ext_vector_type(8))) short bf16x8;
typedef __attribute__((ext_vector_type(4))) short bf16x4;
typedef __attribute__((ext_vector_type(4))) float f32x4;

__device__ __forceinline__ void load16_lds(const void* g, void* l) {
  __builtin_amdgcn_global_load_lds(
      (const __attribute__((address_space(1))) void*)g,
      (__attribute__((address_space(3))) void*)l, 16, 0, 0);
}

__device__ __forceinline__ short bfbits(float x) {
  __hip_bfloat16 h = __float2bfloat16(x);
  return *(short*)&h;
}
__device__ __forceinline__ bf16x8 cvt8(float4 a, float4 b) {
  bf16x8 r;
  r[0] = bfbits(a.x); r[1] = bfbits(a.y); r[2] = bfbits(a.z); r[3] = bfbits(a.w);
  r[4] = bfbits(b.x); r[5] = bfbits(b.y); r[6] = bfbits(b.z); r[7] = bfbits(b.w);
  return r;
}
__device__ __forceinline__ float bf2f(u16 u) {
  unsigned v = (unsigned)u << 16;
  return *(float*)&v;
}

// ---------------------------------------------------------------------------
// 0. weights fp32 -> bf16 (W reused by 32 m-tiles; X handled in-GEMM).
// ---------------------------------------------------------------------------
__global__ __launch_bounds__(256) void cvtW_kernel(
    const float* __restrict__ wq, const float* __restrict__ wk,
    const float* __restrict__ wv, const float* __restrict__ wo,
    u16* __restrict__ Wbf) {
  const int y = blockIdx.y;
  const float* src = y == 0 ? wq : (y == 1 ? wk : (y == 2 ? wv : wo));
  size_t i = ((size_t)blockIdx.x * 256 + threadIdx.x) * 8;
  float4 a = *(const float4*)(src + i);
  float4 b = *(const float4*)(src + i + 4);
  *(bf16x8*)(Wbf + (size_t)y * (HID * HID) + i) = cvt8(a, b);
}

// ---------------------------------------------------------------------------
// 1. pack attention_mask (S x S int32 0/1) -> bitmask.
// ---------------------------------------------------------------------------
__global__ void pack_mask_kernel(const int* __restrict__ mask,
                                 unsigned int* __restrict__ bits) {
  int w = blockIdx.x * blockDim.x + threadIdx.x;
  const int4* p = (const int4*)(mask + (size_t)w * 32);
  unsigned word = 0;
#pragma unroll
  for (int i = 0; i < 8; ++i) {
    int4 v = p[i];
    word |= (unsigned)(v.x != 0) << (i * 4 + 0);
    word |= (unsigned)(v.y != 0) << (i * 4 + 1);
    word |= (unsigned)(v.z != 0) << (i * 4 + 2);
    word |= (unsigned)(v.w != 0) << (i * 4 + 3);
  }
  bits[w] = word;
}

// ---------------------------------------------------------------------------
// 2. QKV GEMM: Y = X @ W^T + b.  BM=64, BN=128, BK=64, 256 thr / 4 waves,
//    grid 768 = 3/CU.  A fp32 (reg prefetch + cvt, dbuf); W bf16 async dbuf.
//    z=0: Y *= 0.125*log2e -> Qb (exp2-folded); z=1 -> Kb; z=2 -> Vt^T.
// ---------------------------------------------------------------------------
__global__ __launch_bounds__(256) void gemm_qkv(
    const float* __restrict__ qf32, const float* __restrict__ kf32,
    const float* __restrict__ vf32, const u16* __restrict__ Wbf,
    const float* __restrict__ bq, const float* __restrict__ bk,
    const float* __restrict__ bv, u16* __restrict__ Qb,
    u16* __restrict__ Kb, u16* __restrict__ Vt) {
  constexpr int Mm = 2048, Nn = 1024, Kk = 1024, NIT = 16;
  const int z = blockIdx.z;
  const float* A = z == 0 ? qf32 : (z == 1 ? kf32 : vf32);
  const u16* W = Wbf + (size_t)z * (HID * HID);
  const float* bias = z == 0 ? bq : (z == 1 ? bk : bv);
  u16* C = z == 0 ? Qb : (z == 1 ? Kb : Vt);
  const float oscale = (z == 0) ? 0.125f * 1.4426950408889634f : 1.0f;
  const int transpose = (z == 2);

  const int tid = threadIdx.x, lane = tid & 63, wave = tid >> 6;
  const int q4 = lane >> 4, c16 = lane & 15;
  const int bx = blockIdx.x;
  const int mBase = (bx & 31) * 64;    // same-XCD blocks share A rows
  const int nBase = (bx >> 5) * 128;
  const int wn = wave * 32;

  __shared__ __align__(16) u16 As[2][2][64 * 32];
  __shared__ __align__(16) u16 Bs[2][2][128 * 32];

  f32x4 acc[4][2] = {};
  const int srow = lane >> 2, se8 = (lane & 3) * 8;

  auto issueW = [&](int it, int buf) {
#pragma unroll
    for (int j = 0; j < 4; ++j) {      // B: 16 units of 1 KB
      int u = wave * 4 + j, h = u >> 3, grp = u & 7;
      load16_lds(W + (size_t)(nBase + grp * 16 + srow) * Kk + it * 64 +
                     h * 32 + se8,
                 &Bs[buf][h][grp * 512]);
    }
  };
  float4 ar[2][2];
  auto loadA = [&](int it) {           // A fp32: global -> regs
#pragma unroll
    for (int j = 0; j < 2; ++j) {      // 8 units, 2 per wave
      int u = wave * 2 + j, h = u >> 2, grp = u & 3;
      const float* s = A + (size_t)(mBase + grp * 16 + srow) * Kk + it * 64 +
                       h * 32 + se8;
      ar[j][0] = *(const float4*)s;
      ar[j][1] = *(const float4*)(s + 4);
    }
  };
  auto storeA = [&](int buf) {         // regs -> cvt -> LDS
#pragma unroll
    for (int j = 0; j < 2; ++j) {
      int u = wave * 2 + j, h = u >> 2, grp = u & 3;
      *(bf16x8*)&As[buf][h][grp * 512 + srow * 32 + se8] =
          cvt8(ar[j][0], ar[j][1]);
    }
  };

  loadA(0);
  storeA(0);
  issueW(0, 0);
  __syncthreads();

  for (int it = 0; it < NIT; ++it) {
    const int buf = it & 1, nbuf = buf ^ 1;
    if (it + 1 < NIT) {
      issueW(it + 1, nbuf);
      loadA(it + 1);
    }
#pragma unroll
    for (int kk = 0; kk < 2; ++kk) {
      bf16x8 af[4], bfr[2];
#pragma unroll
      for (int t = 0; t < 4; ++t)
        af[t] = *(const bf16x8*)&As[buf][kk][(t * 16 + c16) * 32 + q4 * 8];
#pragma unroll
      for (int t = 0; t < 2; ++t)
        bfr[t] = *(const bf16x8*)&Bs[buf][kk][(wn + t * 16 + c16) * 32 + q4 * 8];
#pragma unroll
      for (int mt = 0; mt < 4; ++mt)
#pragma unroll
        for (int nt = 0; nt < 2; ++nt)
          acc[mt][nt] = __builtin_amdgcn_mfma_f32_16x16x32_bf16(
              af[mt], bfr[nt], acc[mt][nt], 0, 0, 0);
    }
    if (it + 1 < NIT) storeA(nbuf);    // after MFMAs; nbuf not read this iter
    __syncthreads();
  }

#pragma unroll
  for (int nt = 0; nt < 2; ++nt) {
    int col = nBase + wn + nt * 16 + c16;
    float bv2 = bias[col];
#pragma unroll
    for (int mt = 0; mt < 4; ++mt) {
#pragma unroll
      for (int r = 0; r < 4; ++r) {
        int row = mBase + mt * 16 + q4 * 4 + r;
        float v = (acc[mt][nt][r] + bv2) * oscale;
        if (transpose)
          ((__hip_bfloat16*)C)[(size_t)col * Mm + row] = __float2bfloat16(v);
        else
          ((__hip_bfloat16*)C)[(size_t)row * Nn + col] = __float2bfloat16(v);
      }
    }
  }
}

// ---------------------------------------------------------------------------
// 3. Attention, no-max softmax via exp2 (Q pre-scaled by 0.125*log2e),
//    KV-split z=2.  64 q-rows / 4 waves / block -> 41 KB LDS -> 3 blocks/CU.
// ---------------------------------------------------------------------------
__global__ __launch_bounds__(256) void attn_kernel(
    const u16* __restrict__ Qb, const u16* __restrict__ Kb,
    const u16* __restrict__ Vt, const unsigned* __restrict__ mbits,
    u16* __restrict__ partO, float* __restrict__ partL) {
  constexpr int NITA = S_LEN / 2 / 64;   // 16
  const int qt = blockIdx.x, h = blockIdx.y, zz = blockIdx.z;
  const int tid = threadIdx.x, lane = tid & 63, wave = tid >> 6;
  const int q4 = lane >> 4, c16 = lane & 15;

  __shared__ __align__(16) u16 Ks[2][2][64 * 32];
  __shared__ __align__(16) u16 Vs[2][2][64 * 32];
  __shared__ __align__(16) u16 Ps[4][16 * 72];

  const int wq0 = qt * 64 + wave * 16;

  bf16x8 qf[2];
#pragma unroll
  for (int kk = 0; kk < 2; ++kk)
    qf[kk] = *(const bf16x8*)(Qb + (size_t)(wq0 + c16) * HID + h * DK +
                              kk * 32 + q4 * 8);

  f32x4 o[4] = {};
  float l_lane[4] = {};

  const int srow = lane >> 2;
  const int se8  = (lane & 3) * 8;
  const int kvbase = zz * (S_LEN / 2);

  auto issueKV = [&](int it, int buf) {
    const int kv0 = kvbase + it * 64;
#pragma unroll
    for (int j = 0; j < 4; ++j) {
      int i = wave * 4 + j;          // 0..15
      if (i < 8) {
        int half = i >> 2, grp = i & 3;
        load16_lds(Kb + (size_t)(kv0 + grp * 16 + srow) * HID + h * DK +
                       half * 32 + se8,
                   &Ks[buf][half][grp * 512]);
      } else {
        int ii = i - 8;
        int half = ii >> 2, grp = ii & 3;
        load16_lds(Vt + (size_t)(h * DK + grp * 16 + srow) * S_LEN + kv0 +
                       half * 32 + se8,
                   &Vs[buf][half][grp * 512]);
      }
    }
  };

  issueKV(0, 0);
  __syncthreads();

  for (int it = 0; it < NITA; ++it) {
    const int buf = it & 1, nbuf = buf ^ 1;
    const int kv0 = kvbase + it * 64;
    if (it + 1 < NITA) issueKV(it + 1, nbuf);

    // S = Q K^T (scores pre-scaled for exp2)
    f32x4 sv[4];
#pragma unroll
    for (int nt = 0; nt < 4; ++nt) {
      bf16x8 kf0 = *(const bf16x8*)&Ks[buf][0][(nt * 16 + c16) * 32 + q4 * 8];
      bf16x8 kf1 = *(const bf16x8*)&Ks[buf][1][(nt * 16 + c16) * 32 + q4 * 8];
      f32x4 a = {};
      a = __builtin_amdgcn_mfma_f32_16x16x32_bf16(qf[0], kf0, a, 0, 0, 0);
      a = __builtin_amdgcn_mfma_f32_16x16x32_bf16(qf[1], kf1, a, 0, 0, 0);
      sv[nt] = a;
    }

    // mask -> 0, p = 2^s  (masked -> 2^0 = 1, the reference quirk)
#pragma unroll
    for (int r = 0; r < 4; ++r) {
      int row = wq0 + q4 * 4 + r;
      const unsigned* mrow = mbits + (size_t)row * 64 + (kv0 >> 5);
      unsigned w0 = mrow[0], w1 = mrow[1];
#pragma unroll
      for (int nt = 0; nt < 4; ++nt) {
        unsigned word = (nt < 2) ? w0 : w1;
        int bit = ((nt & 1) * 16) + c16;
        float s = ((word >> bit) & 1u) ? sv[nt][r] : 0.0f;
        float p = exp2f(s);            // bare v_exp_f32
        sv[nt][r] = p;
        l_lane[r] += p;
      }
    }

    // P: C-layout -> per-wave LDS (stride 72), wave-local ordering
    u16* pw = &Ps[wave][0];
#pragma unroll
    for (int r = 0; r < 4; ++r)
#pragma unroll
      for (int nt = 0; nt < 4; ++nt)
        ((__hip_bfloat16*)pw)[(q4 * 4 + r) * 72 + nt * 16 + c16] =
            __float2bfloat16(sv[nt][r]);
    asm volatile("s_waitcnt lgkmcnt(0)" ::: "memory");

    // O += P V
#pragma unroll
    for (int kk = 0; kk < 2; ++kk) {
      bf16x8 pa = *(const bf16x8*)&pw[c16 * 72 + kk * 32 + q4 * 8];
#pragma unroll
      for (int nt = 0; nt < 4; ++nt) {
        bf16x8 vb = *(const bf16x8*)&Vs[buf][kk][(nt * 16 + c16) * 32 + q4 * 8];
        o[nt] = __builtin_amdgcn_mfma_f32_16x16x32_bf16(pa, vb, o[nt], 0, 0, 0);
      }
    }
    __syncthreads();
  }

#pragma unroll
  for (int r = 0; r < 4; ++r) {
    float s = l_lane[r];
#pragma unroll
    for (int d = 1; d < 16; d <<= 1) s += __shfl_xor(s, d);
    l_lane[r] = s;
  }

#pragma unroll
  for (int r = 0; r < 4; ++r) {
    int row = wq0 + q4 * 4 + r;
#pragma unroll
    for (int nt = 0; nt < 4; ++nt)
      ((__hip_bfloat16*)partO)[((size_t)zz * S_LEN + row) * HID + h * DK +
                               nt * 16 + c16] = __float2bfloat16(o[nt][r]);
    if (c16 == 0)
      partL[((size_t)zz * NHEAD + h) * S_LEN + row] = l_lane[r];
  }
}

// ---------------------------------------------------------------------------
// 4. combine KV-split partials: ctx = (O0 + O1) / (l0 + l1), bf16.
// ---------------------------------------------------------------------------
__global__ __launch_bounds__(256) void combine_kernel(
    const u16* __restrict__ partO, const float* __restrict__ partL,
    u16* __restrict__ ctx) {
  size_t idx = ((size_t)blockIdx.x * 256 + threadIdx.x) * 4;
  int row = (int)(idx >> 10);
  int col = (int)(idx & 1023);
  int h = col >> 6;
  float l = partL[(size_t)h * S_LEN + row] +
            partL[((size_t)NHEAD + h) * S_LEN + row];
  float inv = 1.0f / l;
  bf16x4 a = *(const bf16x4*)(partO + idx);
  bf16x4 b = *(const bf16x4*)(partO + (size_t)S_LEN * HID + idx);
  bf16x4 r;
#pragma unroll
  for (int j = 0; j < 4; ++j) {
    float v = (bf2f((u16)a[j]) + bf2f((u16)b[j])) * inv;
    r[j] = bfbits(v);
  }
  *(bf16x4*)(ctx + idx) = r;
}

// ---------------------------------------------------------------------------
// 5. Output GEMM: out = ctx @ Wo^T + bo, fp32 store.  BM=32, BN=128 ->
//    grid 512 = 2/CU.  256 thr / 4 waves, wave tile 32x32.
// ---------------------------------------------------------------------------
__global__ __launch_bounds__(256) void gemm_out(
    const u16* __restrict__ ctx, const u16* __restrict__ Wo,
    const float* __restrict__ bo, float* __restrict__ out) {
  constexpr int Nn = 1024, Kk = 1024, NIT = 16;
  const int tid = threadIdx.x, lane = tid & 63, wave = tid >> 6;
  const int q4 = lane >> 4, c16 = lane & 15;
  const int bx = blockIdx.x;
  const int mBase = (bx & 63) * 32;    // same-XCD blocks share A rows
  const int nBase = (bx >> 6) * 128;
  const int wn = wave * 32;

  __shared__ __align__(16) u16 As[2][2][32 * 32];
  __shared__ __align__(16) u16 Bs[2][2][128 * 32];

  f32x4 acc[2][2] = {};
  const int srow = lane >> 2, se8 = (lane & 3) * 8;

  auto issue = [&](int it, int buf) {
    {                                   // A: 4 units, 1/wave
      int u = wave, h = u >> 1, grp = u & 1;
      load16_lds(ctx + (size_t)(mBase + grp * 16 + srow) * Kk + it * 64 +
                     h * 32 + se8,
                 &As[buf][h][grp * 512]);
    }
#pragma unroll
    for (int j = 0; j < 4; ++j) {       // B: 16 units
      int u = wave * 4 + j, h = u >> 3, grp = u & 7;
      load16_lds(Wo + (size_t)(nBase + grp * 16 + srow) * Kk + it * 64 +
                     h * 32 + se8,
                 &Bs[buf][h][grp * 512]);
    }
  };

  issue(0, 0);
  __syncthreads();

  for (int it = 0; it < NIT; ++it) {
    const int buf = it & 1, nbuf = buf ^ 1;
    if (it + 1 < NIT) issue(it + 1, nbuf);
#pragma unroll
    for (int kk = 0; kk < 2; ++kk) {
      bf16x8 af[2], bfr[2];
#pragma unroll
      for (int t = 0; t < 2; ++t)
        af[t] = *(const bf16x8*)&As[buf][kk][(t * 16 + c16) * 32 + q4 * 8];
#pragma unroll
      for (int t = 0; t < 2; ++t)
        bfr[t] = *(const bf16x8*)&Bs[buf][kk][(wn + t * 16 + c16) * 32 + q4 * 8];
#pragma unroll
      for (int mt = 0; mt < 2; ++mt)
#pragma unroll
        for (int nt = 0; nt < 2; ++nt)
          acc[mt][nt] = __builtin_amdgcn_mfma_f32_16x16x32_bf16(
              af[mt], bfr[nt], acc[mt][nt], 0, 0, 0);
    }
    __syncthreads();
  }

#pragma unroll
  for (int nt = 0; nt < 2; ++nt) {
    int col = nBase + wn + nt * 16 + c16;
    float bv = bo[col];
#pragma unroll
    for (int mt = 0; mt < 2; ++mt)
#pragma unroll
      for (int r = 0; r < 4; ++r) {
        int row = mBase + mt * 16 + q4 * 4 + r;
        out[(size_t)row * Nn + col] = acc[mt][nt][r] + bv;
      }
  }
}

// ---------------------------------------------------------------------------
extern "C" void kernel_launch(void* const* d_in, const int* in_sizes, int n_in,
                              void* d_out, int out_size, void* d_ws, size_t ws_size,
                              hipStream_t stream) {
  const float* q    = (const float*)d_in[0];
  const float* k    = (const float*)d_in[1];
  const float* v    = (const float*)d_in[2];
  const int*   mask = (const int*)d_in[3];
  const float* Wq = (const float*)d_in[4];
  const float* bq = (const float*)d_in[5];
  const float* Wk = (const float*)d_in[6];
  const float* bk = (const float*)d_in[7];
  const float* Wv = (const float*)d_in[8];
  const float* bv = (const float*)d_in[9];
  const float* Wo = (const float*)d_in[10];
  const float* bo = (const float*)d_in[11];

  const size_t M2 = (size_t)S_LEN * HID;          // 2M elems
  const size_t W1 = (size_t)HID * HID;            // 1M elems
  // Wbf 4M | partO 4M | Qb 2M (->ctx) | Kb 2M | Vt 2M  (u16 elems)
  const size_t need = (4 * W1 + 2 * M2 + 3 * M2) * 2 +
                      (size_t)S_LEN * 64 * 4 + 2 * NHEAD * S_LEN * 4;
  if (ws_size < need) return;   // diagnostic: absmax==0.0752 -> ws too small

  u16* Wbf = (u16*)d_ws;                  // 4M elems
  u16* partO = Wbf + 4 * W1;              // 4M elems (2 kv-splits)
  u16* Qb = partO + 2 * M2;
  u16* Kb = Qb + M2;
  u16* Vt = Kb + M2;
  unsigned* mbits = (unsigned*)(Vt + M2);
  float* partL = (float*)(mbits + (size_t)S_LEN * 64);
  u16* ctx = Qb;   // Qb dead after attn

  hipLaunchKernelGGL(cvtW_kernel, dim3(512, 4), dim3(256), 0, stream,
                     Wq, Wk, Wv, Wo, Wbf);

  hipLaunchKernelGGL(pack_mask_kernel, dim3((S_LEN * (S_LEN / 32)) / 256),
                     dim3(256), 0, stream, mask, mbits);

  hipLaunchKernelGGL(gemm_qkv, dim3(256, 1, 3), dim3(256), 0, stream,
                     q, k, v, Wbf, bq, bk, bv, Qb, Kb, Vt);

  hipLaunchKernelGGL(attn_kernel, dim3(S_LEN / 64, NHEAD, 2), dim3(256), 0,
                     stream, Qb, Kb, Vt, mbits, partO, partL);

  hipLaunchKernelGGL(combine_kernel, dim3((S_LEN * HID / 4) / 256), dim3(256),
                     0, stream, partO, partL, ctx);

  hipLaunchKernelGGL(gemm_out, dim3(512), dim3(256), 0, stream,
                     ctx, Wbf + 3 * W1, bo, (float*)d_out);
}

// Round 10
// 205.982 us; speedup vs baseline: 1.0359x; 1.0359x over previous
//
#include <hip/hip_runtime.h>
#include <hip/hip_bf16.h>

// MHA forward.  B=1, S=2048, H=1024, NH=16, DK=64.
// Inputs fp32, output fp32.  Internal bf16 MFMA pipeline, fp32 accum.
// Quirk: masked scores -> 0 (not -inf) BEFORE softmax; |scores| <= ~2 so
// softmax needs no max subtraction (m=0) and KV-split partials add.
// R10: attn 32q/wave (2 subtiles share K/V frags -> LDS reads per q halve);
// combine fused into gemm_out A-staging; exp2 builtin.

#define S_LEN 2048
#define HID   1024
#define NHEAD 16
#define DK    64

typedef unsigned short u16;
typedef __attribute__((ext_vector_type(8))) short bf16x8;
typedef __attribute__((ext_vector_type(4))) float f32x4;

#if defined(__has_builtin)
#if __has_builtin(__builtin_amdgcn_exp2f)
#define EXP2F(x) __builtin_amdgcn_exp2f(x)
#else
#define EXP2F(x) exp2f(x)
#endif
#else
#define EXP2F(x) exp2f(x)
#endif

__device__ __forceinline__ void load16_lds(const void* g, void* l) {
  __builtin_amdgcn_global_load_lds(
      (const __attribute__((address_space(1))) void*)g,
      (__attribute__((address_space(3))) void*)l, 16, 0, 0);
}

__device__ __forceinline__ short bfbits(float x) {
  __hip_bfloat16 h = __float2bfloat16(x);
  return *(short*)&h;
}
__device__ __forceinline__ bf16x8 cvt8(float4 a, float4 b) {
  bf16x8 r;
  r[0] = bfbits(a.x); r[1] = bfbits(a.y); r[2] = bfbits(a.z); r[3] = bfbits(a.w);
  r[4] = bfbits(b.x); r[5] = bfbits(b.y); r[6] = bfbits(b.z); r[7] = bfbits(b.w);
  return r;
}
__device__ __forceinline__ float bf2f(u16 u) {
  unsigned v = (unsigned)u << 16;
  return *(float*)&v;
}

// ---------------------------------------------------------------------------
// 0. weights fp32 -> bf16 (one-time).
// ---------------------------------------------------------------------------
__global__ __launch_bounds__(256) void cvtW_kernel(
    const float* __restrict__ wq, const float* __restrict__ wk,
    const float* __restrict__ wv, const float* __restrict__ wo,
    u16* __restrict__ Wbf) {
  const int y = blockIdx.y;
  const float* src = y == 0 ? wq : (y == 1 ? wk : (y == 2 ? wv : wo));
  size_t i = ((size_t)blockIdx.x * 256 + threadIdx.x) * 8;
  float4 a = *(const float4*)(src + i);
  float4 b = *(const float4*)(src + i + 4);
  *(bf16x8*)(Wbf + (size_t)y * (HID * HID) + i) = cvt8(a, b);
}

// ---------------------------------------------------------------------------
// 1. pack attention_mask (S x S int32 0/1) -> bitmask.
// ---------------------------------------------------------------------------
__global__ void pack_mask_kernel(const int* __restrict__ mask,
                                 unsigned int* __restrict__ bits) {
  int w = blockIdx.x * blockDim.x + threadIdx.x;
  const int4* p = (const int4*)(mask + (size_t)w * 32);
  unsigned word = 0;
#pragma unroll
  for (int i = 0; i < 8; ++i) {
    int4 v = p[i];
    word |= (unsigned)(v.x != 0) << (i * 4 + 0);
    word |= (unsigned)(v.y != 0) << (i * 4 + 1);
    word |= (unsigned)(v.z != 0) << (i * 4 + 2);
    word |= (unsigned)(v.w != 0) << (i * 4 + 3);
  }
  bits[w] = word;
}

// ---------------------------------------------------------------------------
// 2. QKV GEMM: Y = X @ W^T + b.  BM=64, BN=128, BK=64, 256 thr / 4 waves,
//    grid 768 = 3/CU.  A fp32 (reg prefetch + cvt, dbuf); W bf16 async dbuf.
//    z=0: Y *= 0.125*log2e -> Qb (exp2-folded); z=1 -> Kb; z=2 -> Vt^T.
// ---------------------------------------------------------------------------
__global__ __launch_bounds__(256) void gemm_qkv(
    const float* __restrict__ qf32, const float* __restrict__ kf32,
    const float* __restrict__ vf32, const u16* __restrict__ Wbf,
    const float* __restrict__ bq, const float* __restrict__ bk,
    const float* __restrict__ bv, u16* __restrict__ Qb,
    u16* __restrict__ Kb, u16* __restrict__ Vt) {
  constexpr int Mm = 2048, Nn = 1024, Kk = 1024, NIT = 16;
  const int z = blockIdx.z;
  const float* A = z == 0 ? qf32 : (z == 1 ? kf32 : vf32);
  const u16* W = Wbf + (size_t)z * (HID * HID);
  const float* bias = z == 0 ? bq : (z == 1 ? bk : bv);
  u16* C = z == 0 ? Qb : (z == 1 ? Kb : Vt);
  const float oscale = (z == 0) ? 0.125f * 1.4426950408889634f : 1.0f;
  const int transpose = (z == 2);

  const int tid = threadIdx.x, lane = tid & 63, wave = tid >> 6;
  const int q4 = lane >> 4, c16 = lane & 15;
  const int bx = blockIdx.x;
  const int mBase = (bx & 31) * 64;    // same-XCD blocks share A rows
  const int nBase = (bx >> 5) * 128;
  const int wn = wave * 32;

  __shared__ __align__(16) u16 As[2][2][64 * 32];
  __shared__ __align__(16) u16 Bs[2][2][128 * 32];

  f32x4 acc[4][2] = {};
  const int srow = lane >> 2, se8 = (lane & 3) * 8;

  auto issueW = [&](int it, int buf) {
#pragma unroll
    for (int j = 0; j < 4; ++j) {      // B: 16 units of 1 KB
      int u = wave * 4 + j, h = u >> 3, grp = u & 7;
      load16_lds(W + (size_t)(nBase + grp * 16 + srow) * Kk + it * 64 +
                     h * 32 + se8,
                 &Bs[buf][h][grp * 512]);
    }
  };
  float4 ar[2][2];
  auto loadA = [&](int it) {           // A fp32: global -> regs
#pragma unroll
    for (int j = 0; j < 2; ++j) {      // 8 units, 2 per wave
      int u = wave * 2 + j, h = u >> 2, grp = u & 3;
      const float* s = A + (size_t)(mBase + grp * 16 + srow) * Kk + it * 64 +
                       h * 32 + se8;
      ar[j][0] = *(const float4*)s;
      ar[j][1] = *(const float4*)(s + 4);
    }
  };
  auto storeA = [&](int buf) {         // regs -> cvt -> LDS
#pragma unroll
    for (int j = 0; j < 2; ++j) {
      int u = wave * 2 + j, h = u >> 2, grp = u & 3;
      *(bf16x8*)&As[buf][h][grp * 512 + srow * 32 + se8] =
          cvt8(ar[j][0], ar[j][1]);
    }
  };

  loadA(0);
  storeA(0);
  issueW(0, 0);
  __syncthreads();

  for (int it = 0; it < NIT; ++it) {
    const int buf = it & 1, nbuf = buf ^ 1;
    if (it + 1 < NIT) {
      issueW(it + 1, nbuf);
      loadA(it + 1);
    }
#pragma unroll
    for (int kk = 0; kk < 2; ++kk) {
      bf16x8 af[4], bfr[2];
#pragma unroll
      for (int t = 0; t < 4; ++t)
        af[t] = *(const bf16x8*)&As[buf][kk][(t * 16 + c16) * 32 + q4 * 8];
#pragma unroll
      for (int t = 0; t < 2; ++t)
        bfr[t] = *(const bf16x8*)&Bs[buf][kk][(wn + t * 16 + c16) * 32 + q4 * 8];
#pragma unroll
      for (int mt = 0; mt < 4; ++mt)
#pragma unroll
        for (int nt = 0; nt < 2; ++nt)
          acc[mt][nt] = __builtin_amdgcn_mfma_f32_16x16x32_bf16(
              af[mt], bfr[nt], acc[mt][nt], 0, 0, 0);
    }
    if (it + 1 < NIT) storeA(nbuf);    // after MFMAs; nbuf not read this iter
    __syncthreads();
  }

#pragma unroll
  for (int nt = 0; nt < 2; ++nt) {
    int col = nBase + wn + nt * 16 + c16;
    float bv2 = bias[col];
#pragma unroll
    for (int mt = 0; mt < 4; ++mt) {
#pragma unroll
      for (int r = 0; r < 4; ++r) {
        int row = mBase + mt * 16 + q4 * 4 + r;
        float v = (acc[mt][nt][r] + bv2) * oscale;
        if (transpose)
          ((__hip_bfloat16*)C)[(size_t)col * Mm + row] = __float2bfloat16(v);
        else
          ((__hip_bfloat16*)C)[(size_t)row * Nn + col] = __float2bfloat16(v);
      }
    }
  }
}

// ---------------------------------------------------------------------------
// 3. Attention, no-max softmax via exp2 (Q pre-scaled), KV-split z=2.
//    4 waves x 32 q-rows (2 subtiles of 16 sharing K/V fragments) = 128 q
//    per block; grid 16x16x2 = 512.  LDS 49 KB -> 3 blocks/CU cap.
// ---------------------------------------------------------------------------
__global__ __launch_bounds__(256) void attn_kernel(
    const u16* __restrict__ Qb, const u16* __restrict__ Kb,
    const u16* __restrict__ Vt, const unsigned* __restrict__ mbits,
    u16* __restrict__ partO, float* __restrict__ partL) {
  constexpr int NITA = S_LEN / 2 / 64;   // 16
  const int qt = blockIdx.x, h = blockIdx.y, zz = blockIdx.z;
  const int tid = threadIdx.x, lane = tid & 63, wave = tid >> 6;
  const int q4 = lane >> 4, c16 = lane & 15;

  __shared__ __align__(16) u16 Ks[2][2][64 * 32];
  __shared__ __align__(16) u16 Vs[2][2][64 * 32];
  __shared__ __align__(16) u16 Ps[4][2 * 16 * 72];   // per-wave, 2 subtiles

  const int wq0 = qt * 128 + wave * 32;

  bf16x8 qf[2][2];   // [subtile][kk]
#pragma unroll
  for (int t = 0; t < 2; ++t)
#pragma unroll
    for (int kk = 0; kk < 2; ++kk)
      qf[t][kk] = *(const bf16x8*)(Qb + (size_t)(wq0 + t * 16 + c16) * HID +
                                   h * DK + kk * 32 + q4 * 8);

  f32x4 o[2][4] = {};
  float l_lane[2][4] = {};

  const int srow = lane >> 2;
  const int se8  = (lane & 3) * 8;
  const int kvbase = zz * (S_LEN / 2);

  auto issueKV = [&](int it, int buf) {
    const int kv0 = kvbase + it * 64;
#pragma unroll
    for (int j = 0; j < 4; ++j) {
      int i = wave * 4 + j;          // 0..15
      if (i < 8) {
        int half = i >> 2, grp = i & 3;
        load16_lds(Kb + (size_t)(kv0 + grp * 16 + srow) * HID + h * DK +
                       half * 32 + se8,
                   &Ks[buf][half][grp * 512]);
      } else {
        int ii = i - 8;
        int half = ii >> 2, grp = ii & 3;
        load16_lds(Vt + (size_t)(h * DK + grp * 16 + srow) * S_LEN + kv0 +
                       half * 32 + se8,
                   &Vs[buf][half][grp * 512]);
      }
    }
  };

  issueKV(0, 0);
  __syncthreads();

  for (int it = 0; it < NITA; ++it) {
    const int buf = it & 1, nbuf = buf ^ 1;
    const int kv0 = kvbase + it * 64;
    if (it + 1 < NITA) issueKV(it + 1, nbuf);

    // S = Q K^T : K fragments read once, used by both q-subtiles
    f32x4 sv[2][4];
#pragma unroll
    for (int nt = 0; nt < 4; ++nt) {
      bf16x8 kf0 = *(const bf16x8*)&Ks[buf][0][(nt * 16 + c16) * 32 + q4 * 8];
      bf16x8 kf1 = *(const bf16x8*)&Ks[buf][1][(nt * 16 + c16) * 32 + q4 * 8];
#pragma unroll
      for (int t = 0; t < 2; ++t) {
        f32x4 a = {};
        a = __builtin_amdgcn_mfma_f32_16x16x32_bf16(qf[t][0], kf0, a, 0, 0, 0);
        a = __builtin_amdgcn_mfma_f32_16x16x32_bf16(qf[t][1], kf1, a, 0, 0, 0);
        sv[t][nt] = a;
      }
    }

    // mask -> 0, p = 2^s (masked -> 1), accumulate l per-lane
#pragma unroll
    for (int t = 0; t < 2; ++t)
#pragma unroll
      for (int r = 0; r < 4; ++r) {
        int row = wq0 + t * 16 + q4 * 4 + r;
        const unsigned* mrow = mbits + (size_t)row * 64 + (kv0 >> 5);
        unsigned w0 = mrow[0], w1 = mrow[1];
#pragma unroll
        for (int nt = 0; nt < 4; ++nt) {
          unsigned word = (nt < 2) ? w0 : w1;
          int bit = ((nt & 1) * 16) + c16;
          float s = ((word >> bit) & 1u) ? sv[t][nt][r] : 0.0f;
          float p = EXP2F(s);
          sv[t][nt][r] = p;
          l_lane[t][r] += p;
        }
      }

    // P: C-layout -> per-wave LDS (stride 72), wave-local ordering only
    u16* pw = &Ps[wave][0];
#pragma unroll
    for (int t = 0; t < 2; ++t)
#pragma unroll
      for (int r = 0; r < 4; ++r)
#pragma unroll
        for (int nt = 0; nt < 4; ++nt)
          ((__hip_bfloat16*)pw)[t * 1152 + (q4 * 4 + r) * 72 + nt * 16 + c16] =
              __float2bfloat16(sv[t][nt][r]);
    asm volatile("s_waitcnt lgkmcnt(0)" ::: "memory");

    // O += P V : V fragments read once, used by both q-subtiles
    bf16x8 vb[2][4];
#pragma unroll
    for (int kk = 0; kk < 2; ++kk)
#pragma unroll
      for (int nt = 0; nt < 4; ++nt)
        vb[kk][nt] =
            *(const bf16x8*)&Vs[buf][kk][(nt * 16 + c16) * 32 + q4 * 8];
#pragma unroll
    for (int t = 0; t < 2; ++t)
#pragma unroll
      for (int kk = 0; kk < 2; ++kk) {
        bf16x8 pa = *(const bf16x8*)&pw[t * 1152 + c16 * 72 + kk * 32 + q4 * 8];
#pragma unroll
        for (int nt = 0; nt < 4; ++nt)
          o[t][nt] = __builtin_amdgcn_mfma_f32_16x16x32_bf16(pa, vb[kk][nt],
                                                             o[t][nt], 0, 0, 0);
      }
    __syncthreads();
  }

#pragma unroll
  for (int t = 0; t < 2; ++t)
#pragma unroll
    for (int r = 0; r < 4; ++r) {
      float s = l_lane[t][r];
#pragma unroll
      for (int d = 1; d < 16; d <<= 1) s += __shfl_xor(s, d);
      l_lane[t][r] = s;
    }

#pragma unroll
  for (int t = 0; t < 2; ++t)
#pragma unroll
    for (int r = 0; r < 4; ++r) {
      int row = wq0 + t * 16 + q4 * 4 + r;
#pragma unroll
      for (int nt = 0; nt < 4; ++nt)
        ((__hip_bfloat16*)partO)[((size_t)zz * S_LEN + row) * HID + h * DK +
                                 nt * 16 + c16] = __float2bfloat16(o[t][nt][r]);
      if (c16 == 0)
        partL[((size_t)zz * NHEAD + h) * S_LEN + row] = l_lane[t][r];
    }
}

// ---------------------------------------------------------------------------
// 4. Output GEMM with fused KV-split combine:
//    out = ((O0+O1)/(l0+l1)) @ Wo^T + bo, fp32 store.  BM=32, BN=128 ->
//    grid 512 = 2/CU.  A-staging reads both partO halves + partL (head = it).
// ---------------------------------------------------------------------------
__global__ __launch_bounds__(256) void gemm_out(
    const u16* __restrict__ partO, const float* __restrict__ partL,
    const u16* __restrict__ Wo, const float* __restrict__ bo,
    float* __restrict__ out) {
  constexpr int Nn = 1024, Kk = 1024, NIT = 16;
  constexpr size_t M2 = (size_t)S_LEN * HID;
  const int tid = threadIdx.x, lane = tid & 63, wave = tid >> 6;
  const int q4 = lane >> 4, c16 = lane & 15;
  const int bx = blockIdx.x;
  const int mBase = (bx & 63) * 32;    // same-XCD blocks share A rows
  const int nBase = (bx >> 6) * 128;
  const int wn = wave * 32;

  __shared__ __align__(16) u16 As[2][2][32 * 32];
  __shared__ __align__(16) u16 Bs[2][2][128 * 32];

  f32x4 acc[2][2] = {};
  const int srow = lane >> 2, se8 = (lane & 3) * 8;

  auto issueW = [&](int it, int buf) {
#pragma unroll
    for (int j = 0; j < 4; ++j) {       // B: 16 units
      int u = wave * 4 + j, h = u >> 3, grp = u & 7;
      load16_lds(Wo + (size_t)(nBase + grp * 16 + srow) * Kk + it * 64 +
                     h * 32 + se8,
                 &Bs[buf][h][grp * 512]);
    }
  };
  // A: fused combine.  head index = it (k = it*64 + ...), so
  // inv = 1/(l0+l1) is uniform over this thread's 8-element chunk.
  bf16x8 a0r, a1r;
  float invr;
  auto loadA = [&](int it) {
    int u = wave, h = u >> 1, grp = u & 1;
    int row = mBase + grp * 16 + srow;
    size_t off = (size_t)row * Kk + it * 64 + h * 32 + se8;
    a0r = *(const bf16x8*)(partO + off);
    a1r = *(const bf16x8*)(partO + M2 + off);
    float l = partL[(size_t)it * S_LEN + row] +
              partL[((size_t)NHEAD + it) * S_LEN + row];
    invr = 1.0f / l;
  };
  auto storeA = [&](int buf) {
    int u = wave, h = u >> 1, grp = u & 1;
    bf16x8 r;
#pragma unroll
    for (int j = 0; j < 8; ++j)
      r[j] = bfbits((bf2f((u16)a0r[j]) + bf2f((u16)a1r[j])) * invr);
    *(bf16x8*)&As[buf][h][grp * 512 + srow * 32 + se8] = r;
  };

  loadA(0);
  storeA(0);
  issueW(0, 0);
  __syncthreads();

  for (int it = 0; it < NIT; ++it) {
    const int buf = it & 1, nbuf = buf ^ 1;
    if (it + 1 < NIT) {
      issueW(it + 1, nbuf);
      loadA(it + 1);
    }
#pragma unroll
    for (int kk = 0; kk < 2; ++kk) {
      bf16x8 af[2], bfr[2];
#pragma unroll
      for (int t = 0; t < 2; ++t)
        af[t] = *(const bf16x8*)&As[buf][kk][(t * 16 + c16) * 32 + q4 * 8];
#pragma unroll
      for (int t = 0; t < 2; ++t)
        bfr[t] = *(const bf16x8*)&Bs[buf][kk][(wn + t * 16 + c16) * 32 + q4 * 8];
#pragma unroll
      for (int mt = 0; mt < 2; ++mt)
#pragma unroll
        for (int nt = 0; nt < 2; ++nt)
          acc[mt][nt] = __builtin_amdgcn_mfma_f32_16x16x32_bf16(
              af[mt], bfr[nt], acc[mt][nt], 0, 0, 0);
    }
    if (it + 1 < NIT) storeA(nbuf);
    __syncthreads();
  }

#pragma unroll
  for (int nt = 0; nt < 2; ++nt) {
    int col = nBase + wn + nt * 16 + c16;
    float bv = bo[col];
#pragma unroll
    for (int mt = 0; mt < 2; ++mt)
#pragma unroll
      for (int r = 0; r < 4; ++r) {
        int row = mBase + mt * 16 + q4 * 4 + r;
        out[(size_t)row * Nn + col] = acc[mt][nt][r] + bv;
      }
  }
}

// ---------------------------------------------------------------------------
extern "C" void kernel_launch(void* const* d_in, const int* in_sizes, int n_in,
                              void* d_out, int out_size, void* d_ws, size_t ws_size,
                              hipStream_t stream) {
  const float* q    = (const float*)d_in[0];
  const float* k    = (const float*)d_in[1];
  const float* v    = (const float*)d_in[2];
  const int*   mask = (const int*)d_in[3];
  const float* Wq = (const float*)d_in[4];
  const float* bq = (const float*)d_in[5];
  const float* Wk = (const float*)d_in[6];
  const float* bk = (const float*)d_in[7];
  const float* Wv = (const float*)d_in[8];
  const float* bv = (const float*)d_in[9];
  const float* Wo = (const float*)d_in[10];
  const float* bo = (const float*)d_in[11];

  const size_t M2 = (size_t)S_LEN * HID;          // 2M elems
  const size_t W1 = (size_t)HID * HID;            // 1M elems
  const size_t need = (4 * W1 + 2 * M2 + 3 * M2) * 2 +
                      (size_t)S_LEN * 64 * 4 + 2 * NHEAD * S_LEN * 4;
  if (ws_size < need) return;

  u16* Wbf = (u16*)d_ws;                  // 4M elems
  u16* partO = Wbf + 4 * W1;              // 4M elems (2 kv-splits)
  u16* Qb = partO + 2 * M2;
  u16* Kb = Qb + M2;
  u16* Vt = Kb + M2;
  unsigned* mbits = (unsigned*)(Vt + M2);
  float* partL = (float*)(mbits + (size_t)S_LEN * 64);

  hipLaunchKernelGGL(cvtW_kernel, dim3(512, 4), dim3(256), 0, stream,
                     Wq, Wk, Wv, Wo, Wbf);

  hipLaunchKernelGGL(pack_mask_kernel, dim3((S_LEN * (S_LEN / 32)) / 256),
                     dim3(256), 0, stream, mask, mbits);

  hipLaunchKernelGGL(gemm_qkv, dim3(256, 1, 3), dim3(256), 0, stream,
                     q, k, v, Wbf, bq, bk, bv, Qb, Kb, Vt);

  hipLaunchKernelGGL(attn_kernel, dim3(S_LEN / 128, NHEAD, 2), dim3(256), 0,
                     stream, Qb, Kb, Vt, mbits, partO, partL);

  hipLaunchKernelGGL(gemm_out, dim3(512), dim3(256), 0, stream,
                     partO, partL, Wbf + 3 * W1, bo, (float*)d_out);
}